// Round 3
// baseline (622.331 us; speedup 1.0000x reference)
//
#include <hip/hip_runtime.h>

#define BN_EPS 1e-5f

typedef __bf16 bf16;
typedef __bf16 bf16x8 __attribute__((ext_vector_type(8)));
typedef float f32x4 __attribute__((ext_vector_type(4)));

union F2 { unsigned long long u; float2 f; };

// ================= CSR build: counting sort of edges by dst =================

__global__ void count_kernel(const int* __restrict__ ei, int* __restrict__ deg, int E) {
    int i = blockIdx.x * blockDim.x + threadIdx.x;
    const int stride = gridDim.x * blockDim.x;
    for (; i < E; i += stride) atomicAdd(&deg[ei[E + i]], 1);
}

__global__ void scanA(const int* __restrict__ deg, int* __restrict__ rowStart,
                      int* __restrict__ blockSums, int N) {
    __shared__ int sd[256];
    const int t = threadIdx.x;
    const int idx = blockIdx.x * 1024 + t * 4;
    int d0 = 0, d1 = 0, d2 = 0, d3 = 0;
    if (idx + 3 < N) { int4 v = *(const int4*)&deg[idx]; d0 = v.x; d1 = v.y; d2 = v.z; d3 = v.w; }
    else {
        if (idx     < N) d0 = deg[idx];
        if (idx + 1 < N) d1 = deg[idx + 1];
        if (idx + 2 < N) d2 = deg[idx + 2];
    }
    const int s = d0 + d1 + d2 + d3;
    sd[t] = s;
    __syncthreads();
    #pragma unroll
    for (int off = 1; off < 256; off <<= 1) {
        const int v = (t >= off) ? sd[t - off] : 0;
        __syncthreads();
        sd[t] += v;
        __syncthreads();
    }
    const int ex = sd[t] - s;
    if (idx     < N) rowStart[idx]     = ex;
    if (idx + 1 < N) rowStart[idx + 1] = ex + d0;
    if (idx + 2 < N) rowStart[idx + 2] = ex + d0 + d1;
    if (idx + 3 < N) rowStart[idx + 3] = ex + d0 + d1 + d2;
    if (t == 255) blockSums[blockIdx.x] = sd[255];
}

__global__ void scanB(int* __restrict__ blockSums, int nblk) {
    __shared__ int sd[256];
    const int t = threadIdx.x;
    const int s = (t < nblk) ? blockSums[t] : 0;
    sd[t] = s;
    __syncthreads();
    #pragma unroll
    for (int off = 1; off < 256; off <<= 1) {
        const int v = (t >= off) ? sd[t - off] : 0;
        __syncthreads();
        sd[t] += v;
        __syncthreads();
    }
    if (t < nblk) blockSums[t] = sd[t] - s;
}

__global__ void scanC(int* __restrict__ rowStart, int* __restrict__ cursor,
                      const int* __restrict__ blockSums, int N) {
    int i = blockIdx.x * blockDim.x + threadIdx.x;
    const int stride = gridDim.x * blockDim.x;
    for (; i < N; i += stride) {
        const int v = rowStart[i] + blockSums[i >> 10];
        rowStart[i] = v;
        cursor[i]   = v;
    }
}

__global__ void scatter_kernel(const int* __restrict__ ei, int* __restrict__ cursor,
                               int2* __restrict__ sPair, int E) {
    int i = blockIdx.x * blockDim.x + threadIdx.x;
    const int stride = gridDim.x * blockDim.x;
    for (; i < E; i += stride) {
        const int dst = ei[E + i];
        const int src = ei[i];
        const int pos = atomicAdd(&cursor[dst], 1);
        sPair[pos] = make_int2(i, src);
    }
}

// ============== Weight prep: Wt[c][k] = (bf16)W[k][c] ==============
__global__ void wprep_kernel(const float* __restrict__ W1, const float* __restrict__ W2,
                             bf16* __restrict__ Wt1, bf16* __restrict__ Wt2) {
    const int c = blockIdx.x;     // 128 blocks
    const int k = threadIdx.x;    // 128 threads
    Wt1[c * 128 + k] = (bf16)W1[k * 128 + c];
    Wt2[c * 128 + k] = (bf16)W2[k * 128 + c];
}

// ===== Fused: per-wave gather-aggregate -> bf16 MFMA MLP -> store + BN stats =====
// Each wave owns a 32-node stripe end-to-end: no mid-kernel barriers.
__launch_bounds__(256, 4)
__global__ void fused_kernel(const float* __restrict__ x, const float* __restrict__ ea,
                             const int2* __restrict__ sPair,
                             const int* __restrict__ rowStart, const int* __restrict__ deg,
                             const bf16* __restrict__ Wt1, const float* __restrict__ b1,
                             const bf16* __restrict__ Wt2, const float* __restrict__ b2,
                             float* __restrict__ out, double* __restrict__ stats, int N) {
    __shared__ bf16 Xs[128][136];           // +8 bf16 pad: 2-way max on b128 col reads
    __shared__ float SredS[128];
    __shared__ float SredQ[128];
    const int tid  = threadIdx.x;
    const int lane = tid & 63;
    const int wv   = tid >> 6;              // wave 0..3
    const int base = blockIdx.x * 128;

    if (tid < 128) { SredS[tid] = 0.f; SredQ[tid] = 0.f; }
    __syncthreads();                        // only barrier (at start, free)

    // ---- Phase 0: aggregate h0 = x + sum relu(x[src]+ea[e]) for 32 own nodes ----
    for (int i = 0; i < 32; i++) {
        const int nl = wv * 32 + i;
        const int n = base + nl;
        float2 acc = {0.f, 0.f};
        if (n < N) {
            acc = ((const float2*)(x + (size_t)n * 128))[lane];
            const int rs = rowStart[n];
            const int end = rs + deg[n];
            int j = rs;
            for (; j + 2 <= end; j += 2) {
                const int2 p0 = sPair[j];
                const int2 p1 = sPair[j + 1];
                F2 a0, a1;
                a0.u = __builtin_nontemporal_load((const unsigned long long*)(ea + (size_t)p0.x * 128) + lane);
                a1.u = __builtin_nontemporal_load((const unsigned long long*)(ea + (size_t)p1.x * 128) + lane);
                const float2 x0 = ((const float2*)(x + (size_t)p0.y * 128))[lane];
                const float2 x1 = ((const float2*)(x + (size_t)p1.y * 128))[lane];
                acc.x += fmaxf(a0.f.x + x0.x, 0.f) + fmaxf(a1.f.x + x1.x, 0.f);
                acc.y += fmaxf(a0.f.y + x0.y, 0.f) + fmaxf(a1.f.y + x1.y, 0.f);
            }
            if (j < end) {
                const int2 p0 = sPair[j];
                F2 a0;
                a0.u = __builtin_nontemporal_load((const unsigned long long*)(ea + (size_t)p0.x * 128) + lane);
                const float2 x0 = ((const float2*)(x + (size_t)p0.y * 128))[lane];
                acc.x += fmaxf(a0.f.x + x0.x, 0.f);
                acc.y += fmaxf(a0.f.y + x0.y, 0.f);
            }
        }
        Xs[nl][2 * lane]     = (bf16)acc.x;
        Xs[nl][2 * lane + 1] = (bf16)acc.y;
    }

    // ---- MFMA fragment coords ----
    const int colq = lane & 15;             // col within 16-tile / A row within 16
    const int kq   = lane >> 4;             // 0..3
    f32x4 accm[2][8];
    #pragma unroll
    for (int tr = 0; tr < 2; tr++)
        #pragma unroll
        for (int tc = 0; tc < 8; tc++) accm[tr][tc] = (f32x4){0.f, 0.f, 0.f, 0.f};

    // ---- Layer 1: h1 = relu(h0 @ W1 + b1), h0 rows 32wv..32wv+31 ----
    #pragma unroll
    for (int ks = 0; ks < 4; ks++) {
        const int ko = 32 * ks + kq * 8;
        const bf16x8 a0 = *(const bf16x8*)&Xs[32 * wv + colq][ko];
        const bf16x8 a1 = *(const bf16x8*)&Xs[32 * wv + 16 + colq][ko];
        #pragma unroll
        for (int tc = 0; tc < 8; tc++) {
            const bf16x8 bf = *(const bf16x8*)&Wt1[(size_t)(16 * tc + colq) * 128 + ko];
            accm[0][tc] = __builtin_amdgcn_mfma_f32_16x16x32_bf16(a0, bf, accm[0][tc], 0, 0, 0);
            accm[1][tc] = __builtin_amdgcn_mfma_f32_16x16x32_bf16(a1, bf, accm[1][tc], 0, 0, 0);
        }
    }

    // bias + relu -> write h1 (bf16) back into own stripe of Xs
    #pragma unroll
    for (int tc = 0; tc < 8; tc++) {
        const float bj = b1[16 * tc + colq];
        #pragma unroll
        for (int tr = 0; tr < 2; tr++) {
            #pragma unroll
            for (int r = 0; r < 4; r++) {
                const int row = 32 * wv + 16 * tr + 4 * kq + r;
                Xs[row][16 * tc + colq] = (bf16)fmaxf(accm[tr][tc][r] + bj, 0.f);
            }
        }
    }

    #pragma unroll
    for (int tr = 0; tr < 2; tr++)
        #pragma unroll
        for (int tc = 0; tc < 8; tc++) accm[tr][tc] = (f32x4){0.f, 0.f, 0.f, 0.f};

    // ---- Layer 2: h2 = h1 @ W2 + b2 ----
    #pragma unroll
    for (int ks = 0; ks < 4; ks++) {
        const int ko = 32 * ks + kq * 8;
        const bf16x8 a0 = *(const bf16x8*)&Xs[32 * wv + colq][ko];
        const bf16x8 a1 = *(const bf16x8*)&Xs[32 * wv + 16 + colq][ko];
        #pragma unroll
        for (int tc = 0; tc < 8; tc++) {
            const bf16x8 bf = *(const bf16x8*)&Wt2[(size_t)(16 * tc + colq) * 128 + ko];
            accm[0][tc] = __builtin_amdgcn_mfma_f32_16x16x32_bf16(a0, bf, accm[0][tc], 0, 0, 0);
            accm[1][tc] = __builtin_amdgcn_mfma_f32_16x16x32_bf16(a1, bf, accm[1][tc], 0, 0, 0);
        }
    }

    // ---- Epilogue: store h2 fp32 + per-column sum/sumsq ----
    #pragma unroll
    for (int tc = 0; tc < 8; tc++) {
        const int col = 16 * tc + colq;
        const float bj = b2[col];
        float sv = 0.f, qv = 0.f;
        #pragma unroll
        for (int tr = 0; tr < 2; tr++) {
            #pragma unroll
            for (int r = 0; r < 4; r++) {
                const int n = base + 32 * wv + 16 * tr + 4 * kq + r;
                if (n < N) {
                    const float h2 = accm[tr][tc][r] + bj;
                    out[(size_t)n * 128 + col] = h2;
                    sv += h2; qv += h2 * h2;
                }
            }
        }
        sv += __shfl_xor(sv, 16); qv += __shfl_xor(qv, 16);
        sv += __shfl_xor(sv, 32); qv += __shfl_xor(qv, 32);
        if (kq == 0) {
            atomicAdd(&SredS[col], sv);
            atomicAdd(&SredQ[col], qv);
        }
    }

    __syncthreads();
    if (tid < 128) {
        unsafeAtomicAdd(&stats[tid],       (double)SredS[tid]);
        unsafeAtomicAdd(&stats[128 + tid], (double)SredQ[tid]);
    }
}

// -------- BN prep --------
__global__ void bnprep_kernel(const double* __restrict__ stats, const float* __restrict__ gamma,
                              const float* __restrict__ beta, float* __restrict__ sb, float invN) {
    const int c = threadIdx.x;
    const float mean = (float)(stats[c] * (double)invN);
    const float ex2  = (float)(stats[128 + c] * (double)invN);
    const float var  = ex2 - mean * mean;
    const float rstd = rsqrtf(var + BN_EPS);
    const float sc = rstd * gamma[c];
    sb[c] = sc;
    sb[128 + c] = beta[c] - mean * sc;
}

// -------- BN apply + relu --------
__global__ void bn_kernel(float4* __restrict__ out4, const float* __restrict__ sb, int n4) {
    int i = blockIdx.x * blockDim.x + threadIdx.x;
    const int stride = gridDim.x * blockDim.x;
    for (; i < n4; i += stride) {
        const int c4 = (i & 31) << 2;
        float4 v = out4[i];
        const float4 sc = *(const float4*)&sb[c4];
        const float4 bs = *(const float4*)&sb[128 + c4];
        v.x = fmaxf(fmaf(v.x, sc.x, bs.x), 0.f);
        v.y = fmaxf(fmaf(v.y, sc.y, bs.y), 0.f);
        v.z = fmaxf(fmaf(v.z, sc.z, bs.z), 0.f);
        v.w = fmaxf(fmaf(v.w, sc.w, bs.w), 0.f);
        out4[i] = v;
    }
}

extern "C" void kernel_launch(void* const* d_in, const int* in_sizes, int n_in,
                              void* d_out, int out_size, void* d_ws, size_t ws_size,
                              hipStream_t stream) {
    const float* x     = (const float*)d_in[0];
    const int*   ei    = (const int*)d_in[1];
    const float* ea    = (const float*)d_in[2];
    const float* W1    = (const float*)d_in[3];
    const float* b1    = (const float*)d_in[4];
    const float* W2    = (const float*)d_in[5];
    const float* b2    = (const float*)d_in[6];
    const float* gamma = (const float*)d_in[7];
    const float* beta  = (const float*)d_in[8];
    float* out = (float*)d_out;

    const int N = in_sizes[0] / 128;
    const int E = in_sizes[1] / 2;

    // workspace layout (16B aligned chunks)
    char* w = (char*)d_ws;
    size_t o = 0;
    int* deg = (int*)(w + o);        o += ((size_t)N * 4 + 15) & ~(size_t)15;
    const size_t zeroLen = o + 2048;                 // deg + stats
    double* stats = (double*)(w + o); o += 2048;     // 256 doubles
    float*  sb    = (float*)(w + o);  o += 1024;     // 256 floats
    int* rowStart = (int*)(w + o);    o += ((size_t)N * 4 + 15) & ~(size_t)15;
    int* cursor   = (int*)(w + o);    o += ((size_t)N * 4 + 15) & ~(size_t)15;
    int* blockSums= (int*)(w + o);    o += 1024;
    int2* sPair   = (int2*)(w + o);   o += (size_t)E * 8;
    bf16* Wt1     = (bf16*)(w + o);   o += 32768;
    bf16* Wt2     = (bf16*)(w + o);

    hipMemsetAsync(d_ws, 0, zeroLen, stream);

    wprep_kernel<<<128, 128, 0, stream>>>(W1, W2, Wt1, Wt2);

    const int nblk = (N + 1023) / 1024;
    count_kernel<<<2048, 256, 0, stream>>>(ei, deg, E);
    scanA<<<nblk, 256, 0, stream>>>(deg, rowStart, blockSums, N);
    scanB<<<1, 256, 0, stream>>>(blockSums, nblk);
    scanC<<<256, 256, 0, stream>>>(rowStart, cursor, blockSums, N);
    scatter_kernel<<<2048, 256, 0, stream>>>(ei, cursor, sPair, E);

    fused_kernel<<<(N + 127) / 128, 256, 0, stream>>>(x, ea, sPair, rowStart, deg,
                                                      Wt1, b1, Wt2, b2, out, stats, N);

    bnprep_kernel<<<1, 128, 0, stream>>>(stats, gamma, beta, sb, 1.0f / (float)N);

    bn_kernel<<<2048, 256, 0, stream>>>((float4*)out, sb, N * 32);
}

// Round 5
// 496.815 us; speedup vs baseline: 1.2526x; 1.2526x over previous
//
#include <hip/hip_runtime.h>

#define BN_EPS 1e-5f

typedef __bf16 bf16;
typedef __bf16 bf16x8 __attribute__((ext_vector_type(8)));
typedef __bf16 bf16x4 __attribute__((ext_vector_type(4)));
typedef float f32x4 __attribute__((ext_vector_type(4)));

// ================= x -> bf16 copy =================
__global__ void xprep_kernel(const float4* __restrict__ x4, bf16x4* __restrict__ xb4, int n4) {
    int i = blockIdx.x * blockDim.x + threadIdx.x;
    const int stride = gridDim.x * blockDim.x;
    for (; i < n4; i += stride) {
        const float4 v = x4[i];
        bf16x4 o;
        o[0] = (bf16)v.x; o[1] = (bf16)v.y; o[2] = (bf16)v.z; o[3] = (bf16)v.w;
        xb4[i] = o;
    }
}

// ============== Weight prep: Wt[c][k] = (bf16)W[k][c] ==============
__global__ void wprep_kernel(const float* __restrict__ W1, const float* __restrict__ W2,
                             bf16* __restrict__ Wt1, bf16* __restrict__ Wt2) {
    const int c = blockIdx.x;
    const int k = threadIdx.x;
    Wt1[c * 128 + k] = (bf16)W1[k * 128 + c];
    Wt2[c * 128 + k] = (bf16)W2[k * 128 + c];
}

// ================= CSR build: counting sort of edges by dst =================
__global__ void count_kernel(const int* __restrict__ ei, int* __restrict__ deg, int E) {
    int i = blockIdx.x * blockDim.x + threadIdx.x;
    const int stride = gridDim.x * blockDim.x;
    for (; i < E; i += stride) atomicAdd(&deg[ei[E + i]], 1);
}

__global__ void scanA(const int* __restrict__ deg, int* __restrict__ rowStart,
                      int* __restrict__ blockSums, int N) {
    __shared__ int sd[256];
    const int t = threadIdx.x;
    const int idx = blockIdx.x * 1024 + t * 4;
    int d0 = 0, d1 = 0, d2 = 0, d3 = 0;
    if (idx + 3 < N) { int4 v = *(const int4*)&deg[idx]; d0 = v.x; d1 = v.y; d2 = v.z; d3 = v.w; }
    else {
        if (idx     < N) d0 = deg[idx];
        if (idx + 1 < N) d1 = deg[idx + 1];
        if (idx + 2 < N) d2 = deg[idx + 2];
    }
    const int s = d0 + d1 + d2 + d3;
    sd[t] = s;
    __syncthreads();
    #pragma unroll
    for (int off = 1; off < 256; off <<= 1) {
        const int v = (t >= off) ? sd[t - off] : 0;
        __syncthreads();
        sd[t] += v;
        __syncthreads();
    }
    const int ex = sd[t] - s;
    if (idx     < N) rowStart[idx]     = ex;
    if (idx + 1 < N) rowStart[idx + 1] = ex + d0;
    if (idx + 2 < N) rowStart[idx + 2] = ex + d0 + d1;
    if (idx + 3 < N) rowStart[idx + 3] = ex + d0 + d1 + d2;
    if (t == 255) blockSums[blockIdx.x] = sd[255];
}

__global__ void scanB(int* __restrict__ blockSums, int nblk) {
    __shared__ int sd[256];
    const int t = threadIdx.x;
    const int s = (t < nblk) ? blockSums[t] : 0;
    sd[t] = s;
    __syncthreads();
    #pragma unroll
    for (int off = 1; off < 256; off <<= 1) {
        const int v = (t >= off) ? sd[t - off] : 0;
        __syncthreads();
        sd[t] += v;
        __syncthreads();
    }
    if (t < nblk) blockSums[t] = sd[t] - s;
}

__global__ void scanC(int* __restrict__ rowStart, int* __restrict__ cursor,
                      const int* __restrict__ blockSums, int N) {
    int i = blockIdx.x * blockDim.x + threadIdx.x;
    const int stride = gridDim.x * blockDim.x;
    for (; i < N; i += stride) {
        const int v = rowStart[i] + blockSums[i >> 10];
        rowStart[i] = v;
        cursor[i]   = v;
    }
}

__global__ void scatter_kernel(const int* __restrict__ ei, int* __restrict__ cursor,
                               int2* __restrict__ sPair, int E) {
    int i = blockIdx.x * blockDim.x + threadIdx.x;
    const int stride = gridDim.x * blockDim.x;
    for (; i < E; i += stride) {
        const int dst = ei[E + i];
        const int src = ei[i];
        const int pos = atomicAdd(&cursor[dst], 1);
        sPair[pos] = make_int2(i, src);
    }
}

// ============ Gather-aggregate: h0b[n] = bf16( x[n] + sum relu(x[src]+ea[e]) ) ============
// one wave per node; half-wave float4 chunks; 4 edges in flight per iteration
__launch_bounds__(256)
__global__ void agg_kernel(const float* __restrict__ x, const bf16* __restrict__ xb,
                           const float* __restrict__ ea, const int2* __restrict__ sPair,
                           const int* __restrict__ rowStart, const int* __restrict__ deg,
                           bf16* __restrict__ h0b, int N) {
    const int wid = (blockIdx.x * blockDim.x + threadIdx.x) >> 6;
    if (wid >= N) return;
    const int lane = threadIdx.x & 63;
    const int half = lane >> 5;      // which edge of a pair
    const int c    = lane & 31;      // float4 chunk of the 128-wide row

    const int rs = rowStart[wid];
    const int dg = deg[wid];

    f32x4 acc = {0.f, 0.f, 0.f, 0.f};

    int done = 0;
    while (done < dg) {
        const int batch = (dg - done < 64) ? (dg - done) : 64;
        int2 p = make_int2(0, 0);
        if (lane < batch) p = sPair[rs + done + lane];
        int i = 0;
        for (; i + 4 <= batch; i += 4) {
            const int eA = __shfl(p.x, i + half);
            const int sA = __shfl(p.y, i + half);
            const int eB = __shfl(p.x, i + 2 + half);
            const int sB = __shfl(p.y, i + 2 + half);
            const f32x4 a0 = __builtin_nontemporal_load((const f32x4*)ea + (((size_t)eA) << 5) + c);
            const bf16x4 x0 = *((const bf16x4*)xb + (((size_t)sA) << 5) + c);
            const f32x4 a1 = __builtin_nontemporal_load((const f32x4*)ea + (((size_t)eB) << 5) + c);
            const bf16x4 x1 = *((const bf16x4*)xb + (((size_t)sB) << 5) + c);
            acc[0] += fmaxf(a0[0] + (float)x0[0], 0.f) + fmaxf(a1[0] + (float)x1[0], 0.f);
            acc[1] += fmaxf(a0[1] + (float)x0[1], 0.f) + fmaxf(a1[1] + (float)x1[1], 0.f);
            acc[2] += fmaxf(a0[2] + (float)x0[2], 0.f) + fmaxf(a1[2] + (float)x1[2], 0.f);
            acc[3] += fmaxf(a0[3] + (float)x0[3], 0.f) + fmaxf(a1[3] + (float)x1[3], 0.f);
        }
        if (i + 2 <= batch) {
            const int eA = __shfl(p.x, i + half);
            const int sA = __shfl(p.y, i + half);
            const f32x4 a0 = __builtin_nontemporal_load((const f32x4*)ea + (((size_t)eA) << 5) + c);
            const bf16x4 x0 = *((const bf16x4*)xb + (((size_t)sA) << 5) + c);
            acc[0] += fmaxf(a0[0] + (float)x0[0], 0.f);
            acc[1] += fmaxf(a0[1] + (float)x0[1], 0.f);
            acc[2] += fmaxf(a0[2] + (float)x0[2], 0.f);
            acc[3] += fmaxf(a0[3] + (float)x0[3], 0.f);
            i += 2;
        }
        if (i < batch) {
            const int eA = __shfl(p.x, i);
            const int sA = __shfl(p.y, i);
            if (half == 0) {
                const f32x4 a0 = __builtin_nontemporal_load((const f32x4*)ea + (((size_t)eA) << 5) + c);
                const bf16x4 x0 = *((const bf16x4*)xb + (((size_t)sA) << 5) + c);
                acc[0] += fmaxf(a0[0] + (float)x0[0], 0.f);
                acc[1] += fmaxf(a0[1] + (float)x0[1], 0.f);
                acc[2] += fmaxf(a0[2] + (float)x0[2], 0.f);
                acc[3] += fmaxf(a0[3] + (float)x0[3], 0.f);
            }
        }
        done += batch;
    }

    // combine halves
    acc[0] += __shfl_xor(acc[0], 32);
    acc[1] += __shfl_xor(acc[1], 32);
    acc[2] += __shfl_xor(acc[2], 32);
    acc[3] += __shfl_xor(acc[3], 32);

    if (half == 0) {
        const f32x4 xv = *((const f32x4*)x + (((size_t)wid) << 5) + c);
        bf16x4 o;
        o[0] = (bf16)(acc[0] + xv[0]);
        o[1] = (bf16)(acc[1] + xv[1]);
        o[2] = (bf16)(acc[2] + xv[2]);
        o[3] = (bf16)(acc[3] + xv[3]);
        *((bf16x4*)h0b + (((size_t)wid) << 5) + c) = o;
    }
}

// ===== MFMA MLP: h2 = relu(h0@W1+b1)@W2+b2, + BN stats. Per-wave 32-row stripe. =====
__launch_bounds__(256, 1)
__global__ void mlp_kernel(const bf16* __restrict__ h0b,
                           const bf16* __restrict__ Wt1, const float* __restrict__ b1,
                           const bf16* __restrict__ Wt2, const float* __restrict__ b2,
                           float* __restrict__ out, double* __restrict__ stats, int N) {
    __shared__ bf16 Xs[128][136];
    __shared__ float SredS[4][128];
    __shared__ float SredQ[4][128];
    const int tid  = threadIdx.x;
    const int lane = tid & 63;
    const int wv   = tid >> 6;
    const int base = blockIdx.x * 128;

    // each wave loads its OWN 32-row stripe: no barrier before compute
    {
        const int r  = tid >> 1;             // rows 32wv .. 32wv+31
        const int c0 = (tid & 1) * 64;
        const int n  = base + r;
        bf16x8* dst = (bf16x8*)&Xs[r][c0];
        if (n < N) {
            const bf16x8* src = (const bf16x8*)(h0b + (size_t)n * 128 + c0);
            #pragma unroll
            for (int q = 0; q < 8; q++) dst[q] = src[q];
        } else {
            bf16x8 z;
            #pragma unroll
            for (int k = 0; k < 8; k++) z[k] = (bf16)0.f;
            #pragma unroll
            for (int q = 0; q < 8; q++) dst[q] = z;
        }
    }

    const int colq = lane & 15;
    const int kq   = lane >> 4;
    f32x4 accm[2][8];
    #pragma unroll
    for (int tr = 0; tr < 2; tr++)
        #pragma unroll
        for (int tc = 0; tc < 8; tc++) accm[tr][tc] = (f32x4){0.f, 0.f, 0.f, 0.f};

    // ---- Layer 1 ----
    #pragma unroll
    for (int ks = 0; ks < 4; ks++) {
        const int ko = 32 * ks + kq * 8;
        const bf16x8 a0 = *(const bf16x8*)&Xs[32 * wv + colq][ko];
        const bf16x8 a1 = *(const bf16x8*)&Xs[32 * wv + 16 + colq][ko];
        #pragma unroll
        for (int tc = 0; tc < 8; tc++) {
            const bf16x8 bf = *(const bf16x8*)&Wt1[(size_t)(16 * tc + colq) * 128 + ko];
            accm[0][tc] = __builtin_amdgcn_mfma_f32_16x16x32_bf16(a0, bf, accm[0][tc], 0, 0, 0);
            accm[1][tc] = __builtin_amdgcn_mfma_f32_16x16x32_bf16(a1, bf, accm[1][tc], 0, 0, 0);
        }
    }

    // bias + relu -> h1 (bf16) back into own stripe
    #pragma unroll
    for (int tc = 0; tc < 8; tc++) {
        const float bj = b1[16 * tc + colq];
        #pragma unroll
        for (int tr = 0; tr < 2; tr++) {
            #pragma unroll
            for (int r = 0; r < 4; r++) {
                const int row = 32 * wv + 16 * tr + 4 * kq + r;
                Xs[row][16 * tc + colq] = (bf16)fmaxf(accm[tr][tc][r] + bj, 0.f);
            }
        }
    }

    #pragma unroll
    for (int tr = 0; tr < 2; tr++)
        #pragma unroll
        for (int tc = 0; tc < 8; tc++) accm[tr][tc] = (f32x4){0.f, 0.f, 0.f, 0.f};

    // ---- Layer 2 ----
    #pragma unroll
    for (int ks = 0; ks < 4; ks++) {
        const int ko = 32 * ks + kq * 8;
        const bf16x8 a0 = *(const bf16x8*)&Xs[32 * wv + colq][ko];
        const bf16x8 a1 = *(const bf16x8*)&Xs[32 * wv + 16 + colq][ko];
        #pragma unroll
        for (int tc = 0; tc < 8; tc++) {
            const bf16x8 bf = *(const bf16x8*)&Wt2[(size_t)(16 * tc + colq) * 128 + ko];
            accm[0][tc] = __builtin_amdgcn_mfma_f32_16x16x32_bf16(a0, bf, accm[0][tc], 0, 0, 0);
            accm[1][tc] = __builtin_amdgcn_mfma_f32_16x16x32_bf16(a1, bf, accm[1][tc], 0, 0, 0);
        }
    }

    // ---- Epilogue: store h2 fp32 + per-column sum/sumsq ----
    #pragma unroll
    for (int tc = 0; tc < 8; tc++) {
        const int col = 16 * tc + colq;
        const float bj = b2[col];
        float sv = 0.f, qv = 0.f;
        #pragma unroll
        for (int tr = 0; tr < 2; tr++) {
            #pragma unroll
            for (int r = 0; r < 4; r++) {
                const int n = base + 32 * wv + 16 * tr + 4 * kq + r;
                if (n < N) {
                    const float h2 = accm[tr][tc][r] + bj;
                    out[(size_t)n * 128 + col] = h2;
                    sv += h2; qv += h2 * h2;
                }
            }
        }
        sv += __shfl_xor(sv, 16); qv += __shfl_xor(qv, 16);
        sv += __shfl_xor(sv, 32); qv += __shfl_xor(qv, 32);
        if (kq == 0) {
            SredS[wv][col] = sv;
            SredQ[wv][col] = qv;
        }
    }

    __syncthreads();
    if (tid < 128) {
        const float ss = SredS[0][tid] + SredS[1][tid] + SredS[2][tid] + SredS[3][tid];
        const float qq = SredQ[0][tid] + SredQ[1][tid] + SredQ[2][tid] + SredQ[3][tid];
        unsafeAtomicAdd(&stats[tid],       (double)ss);
        unsafeAtomicAdd(&stats[128 + tid], (double)qq);
    }
}

// -------- BN prep --------
__global__ void bnprep_kernel(const double* __restrict__ stats, const float* __restrict__ gamma,
                              const float* __restrict__ beta, float* __restrict__ sb, float invN) {
    const int c = threadIdx.x;
    const float mean = (float)(stats[c] * (double)invN);
    const float ex2  = (float)(stats[128 + c] * (double)invN);
    const float var  = ex2 - mean * mean;
    const float rstd = rsqrtf(var + BN_EPS);
    const float sc = rstd * gamma[c];
    sb[c] = sc;
    sb[128 + c] = beta[c] - mean * sc;
}

// -------- BN apply + relu --------
__global__ void bn_kernel(float4* __restrict__ out4, const float* __restrict__ sb, int n4) {
    int i = blockIdx.x * blockDim.x + threadIdx.x;
    const int stride = gridDim.x * blockDim.x;
    for (; i < n4; i += stride) {
        const int c4 = (i & 31) << 2;
        float4 v = out4[i];
        const float4 sc = *(const float4*)&sb[c4];
        const float4 bs = *(const float4*)&sb[128 + c4];
        v.x = fmaxf(fmaf(v.x, sc.x, bs.x), 0.f);
        v.y = fmaxf(fmaf(v.y, sc.y, bs.y), 0.f);
        v.z = fmaxf(fmaf(v.z, sc.z, bs.z), 0.f);
        v.w = fmaxf(fmaf(v.w, sc.w, bs.w), 0.f);
        out4[i] = v;
    }
}

extern "C" void kernel_launch(void* const* d_in, const int* in_sizes, int n_in,
                              void* d_out, int out_size, void* d_ws, size_t ws_size,
                              hipStream_t stream) {
    const float* x     = (const float*)d_in[0];
    const int*   ei    = (const int*)d_in[1];
    const float* ea    = (const float*)d_in[2];
    const float* W1    = (const float*)d_in[3];
    const float* b1    = (const float*)d_in[4];
    const float* W2    = (const float*)d_in[5];
    const float* b2    = (const float*)d_in[6];
    const float* gamma = (const float*)d_in[7];
    const float* beta  = (const float*)d_in[8];
    float* out = (float*)d_out;

    const int N = in_sizes[0] / 128;
    const int E = in_sizes[1] / 2;

    // workspace layout (16B aligned)
    char* w = (char*)d_ws;
    size_t o = 0;
    int* deg = (int*)(w + o);         o += ((size_t)N * 4 + 15) & ~(size_t)15;
    const size_t zeroLen = o + 2048;  // deg + stats
    double* stats = (double*)(w + o); o += 2048;
    float*  sb    = (float*)(w + o);  o += 1024;
    int* rowStart = (int*)(w + o);    o += ((size_t)N * 4 + 15) & ~(size_t)15;
    int* cursor   = (int*)(w + o);    o += ((size_t)N * 4 + 15) & ~(size_t)15;
    int* blockSums= (int*)(w + o);    o += 1024;
    int2* sPair   = (int2*)(w + o);   o += (size_t)E * 8;
    bf16* Wt1     = (bf16*)(w + o);   o += 32768;
    bf16* Wt2     = (bf16*)(w + o);   o += 32768;
    bf16* xb      = (bf16*)(w + o);   o += (size_t)N * 128 * 2;
    bf16* h0b     = (bf16*)(w + o);   o += (size_t)N * 128 * 2;

    hipMemsetAsync(d_ws, 0, zeroLen, stream);

    xprep_kernel<<<2048, 256, 0, stream>>>((const float4*)x, (bf16x4*)xb, N * 32);
    wprep_kernel<<<128, 128, 0, stream>>>(W1, W2, Wt1, Wt2);

    const int nblk = (N + 1023) / 1024;
    count_kernel<<<2048, 256, 0, stream>>>(ei, deg, E);
    scanA<<<nblk, 256, 0, stream>>>(deg, rowStart, blockSums, N);
    scanB<<<1, 256, 0, stream>>>(blockSums, nblk);
    scanC<<<256, 256, 0, stream>>>(rowStart, cursor, blockSums, N);
    scatter_kernel<<<2048, 256, 0, stream>>>(ei, cursor, sPair, E);

    agg_kernel<<<(N * 64 + 255) / 256, 256, 0, stream>>>(x, xb, ea, sPair, rowStart, deg, h0b, N);

    mlp_kernel<<<(N + 127) / 128, 256, 0, stream>>>(h0b, Wt1, b1, Wt2, b2, out, stats, N);

    bnprep_kernel<<<1, 128, 0, stream>>>(stats, gamma, beta, sb, 1.0f / (float)N);

    bn_kernel<<<2048, 256, 0, stream>>>((float4*)out, sb, N * 32);
}